// Round 6
// baseline (298.624 us; speedup 1.0000x reference)
//
#include <hip/hip_runtime.h>

#define B_SZ 4
#define SEQ  4096
#define DM   1024
#define DSTATE 16
#define ROWS (B_SZ*SEQ)   // 16384

typedef unsigned short u16;
typedef __attribute__((ext_vector_type(8))) short   s16x8;   // 8 bf16 (4 VGPRs)
typedef __attribute__((ext_vector_type(4))) float   f32x4;
typedef __attribute__((ext_vector_type(4))) u16     u16x4;

__device__ inline float bf2f(u16 u) {
    unsigned v = ((unsigned)u) << 16;
    float f; __builtin_memcpy(&f, &v, 4); return f;
}
__device__ inline u16 f2bf(float f) {
    unsigned u; __builtin_memcpy(&u, &f, 4);
    return (u16)((u + 0x7FFFu + ((u >> 16) & 1u)) >> 16);   // RNE
}
__device__ inline f32x4 mfma16(s16x8 a, s16x8 b, f32x4 c) {
    return __builtin_amdgcn_mfma_f32_16x16x32_bf16(a, b, c, 0, 0, 0);
}
// async global->LDS, 16B per lane, dest = wave-uniform base + lane*16
__device__ inline void gl_lds16(const u16* g, u16* l) {
    __builtin_amdgcn_global_load_lds(
        (const __attribute__((address_space(1))) unsigned int*)g,
        (__attribute__((address_space(3))) unsigned int*)l, 16, 0, 0);
}

// ---------------------------------------------------------------------------
// K0a: x fp32 -> (xh, xl) bf16 split.  x = xh + xl + O(2^-18 |x|)
// (xl feeds only k_bxcx's 3-pass split — Bx/Cx precision is scan-amplified.)
// ---------------------------------------------------------------------------
__global__ __launch_bounds__(256) void k_cvt_split(
    const float* __restrict__ in, u16* __restrict__ oh, u16* __restrict__ ol, int n4)
{
    int i = blockIdx.x * 256 + threadIdx.x;
    if (i < n4) {
        f32x4 v = ((const f32x4*)in)[i];
        u16x4 h, l;
#pragma unroll
        for (int c = 0; c < 4; c++) {
            h[c] = f2bf(v[c]);
            l[c] = f2bf(v[c] - bf2f(h[c]));
        }
        ((u16x4*)oh)[i] = h;
        ((u16x4*)ol)[i] = l;
    }
}

// ---------------------------------------------------------------------------
// K0b: weight conversions in one launch.
// blocks [0,1024): gw -> gwb (bf16).  [1024,1040): Bw split. [1040,1056): Cw.
// ---------------------------------------------------------------------------
__global__ __launch_bounds__(256) void k_cvt_w(
    const float* __restrict__ gw, const float* __restrict__ Bw,
    const float* __restrict__ Cw, u16* __restrict__ gwb,
    u16* __restrict__ bwh, u16* __restrict__ bwl,
    u16* __restrict__ cwh, u16* __restrict__ cwl)
{
    int blk = blockIdx.x;
    if (blk < 1024) {
        int i = blk * 256 + threadIdx.x;
        f32x4 v = ((const f32x4*)gw)[i];
        u16x4 o;
#pragma unroll
        for (int c = 0; c < 4; c++) o[c] = f2bf(v[c]);
        ((u16x4*)gwb)[i] = o;
    } else {
        int isC = (blk >= 1040);
        const float* src = isC ? Cw : Bw;
        u16* dh = isC ? cwh : bwh;
        u16* dl = isC ? cwl : bwl;
        int i = (blk - (isC ? 1040 : 1024)) * 256 + threadIdx.x;
        f32x4 v = ((const f32x4*)src)[i];
        u16x4 h, l;
#pragma unroll
        for (int c = 0; c < 4; c++) {
            h[c] = f2bf(v[c]);
            l[c] = f2bf(v[c] - bf2f(h[c]));
        }
        ((u16x4*)dh)[i] = h;
        ((u16x4*)dl)[i] = l;
    }
}

// ---------------------------------------------------------------------------
// K1: Bx/Cx = x @ B_w^T, x @ C_w^T, 3-pass split-bf16 MFMA (fp32-grade).
// One wave per 16-row M-tile -> 1024 single-wave blocks.
// ---------------------------------------------------------------------------
__global__ __launch_bounds__(64) void k_bxcx(
    const u16* __restrict__ xh, const u16* __restrict__ xl,
    const u16* __restrict__ bwh, const u16* __restrict__ bwl,
    const u16* __restrict__ cwh, const u16* __restrict__ cwl,
    float* __restrict__ Bx, float* __restrict__ Cx)
{
    int lane = threadIdx.x;
    int lo = lane & 15, hi = lane >> 4;
    int m0 = blockIdx.x * 16;
    f32x4 accB = {}, accC = {};
    for (int k0 = 0; k0 < DM; k0 += 32) {
        size_t woff = (size_t)lo * DM + k0 + hi * 8;
        s16x8 bh = *(const s16x8*)(bwh + woff);
        s16x8 bl = *(const s16x8*)(bwl + woff);
        s16x8 ch = *(const s16x8*)(cwh + woff);
        s16x8 cl = *(const s16x8*)(cwl + woff);
        size_t aoff = (size_t)(m0 + lo) * DM + k0 + hi * 8;
        s16x8 ah = *(const s16x8*)(xh + aoff);
        s16x8 al = *(const s16x8*)(xl + aoff);
        accB = mfma16(ah, bh, accB);
        accB = mfma16(al, bh, accB);
        accB = mfma16(ah, bl, accB);
        accC = mfma16(ah, ch, accC);
        accC = mfma16(al, ch, accC);
        accC = mfma16(ah, cl, accC);
    }
#pragma unroll
    for (int r = 0; r < 4; r++) {
        int m = m0 + hi * 4 + r;
        Bx[(size_t)m * DSTATE + lo] = accB[r];
        Cx[(size_t)m * DSTATE + lo] = accC[r];
    }
}

// ---------------------------------------------------------------------------
// K2: gate = sigmoid(x @ gate_w^T + gate_b), bf16 out (ws, aliased over xl —
// xl is dead after k_bxcx which precedes this kernel on the stream).
// 128x128 tile, BK=64, global_load_lds w=16, XOR-swizzled 16B chunks.
// ---------------------------------------------------------------------------
#define BM 128
#define BN 128
#define BK 64

__global__ __launch_bounds__(256) void k_gate(
    const u16* __restrict__ xh, const u16* __restrict__ gwb,
    const float* __restrict__ gb, u16* __restrict__ gate)
{
    __shared__ u16 sA[BM * BK], sB[BN * BK];   // 16 KB + 16 KB
    int tid = threadIdx.x;
    int wv = tid >> 6, lane = tid & 63;
    int lo = lane & 15, hi = lane >> 4;
    int m0 = blockIdx.x * BM;
    int n0 = blockIdx.y * BN;

    int r_in = lane >> 3;          // row within 1KB staging issue (8 rows)
    int p    = lane & 7;           // physical 16B chunk slot in LDS row
    int c    = p ^ r_in;           // swizzled source chunk

    int mrow = (wv & 1) * 64;
    int ncol = (wv >> 1) * 64;

    f32x4 acc[4][4] = {};
    for (int k0 = 0; k0 < DM; k0 += BK) {
        __syncthreads();
#pragma unroll
        for (int q = 0; q < 4; q++) {
            int r = (wv * 4 + q) * 8 + r_in;            // 0..127
            size_t goff = (size_t)r * DM + k0 + c * 8;
            gl_lds16(xh  + (size_t)m0 * DM + goff, &sA[(wv * 4 + q) * 512]);
            gl_lds16(gwb + (size_t)n0 * DM + goff, &sB[(wv * 4 + q) * 512]);
        }
        __syncthreads();
#pragma unroll
        for (int kk = 0; kk < 2; kk++) {
            s16x8 bfr[4], afr[4];
#pragma unroll
            for (int j = 0; j < 4; j++) {
                int rb = ncol + j * 16 + lo;
                int pc = (kk * 4 + hi) ^ (rb & 7);
                bfr[j] = *(const s16x8*)&sB[rb * BK + pc * 8];
            }
#pragma unroll
            for (int i = 0; i < 4; i++) {
                int ra = mrow + i * 16 + lo;
                int pc = (kk * 4 + hi) ^ (ra & 7);
                afr[i] = *(const s16x8*)&sA[ra * BK + pc * 8];
            }
#pragma unroll
            for (int i = 0; i < 4; i++)
#pragma unroll
                for (int j = 0; j < 4; j++)
                    acc[i][j] = mfma16(afr[i], bfr[j], acc[i][j]);
        }
    }
#pragma unroll
    for (int i = 0; i < 4; i++)
#pragma unroll
        for (int r = 0; r < 4; r++) {
            int m = m0 + mrow + i * 16 + hi * 4 + r;
#pragma unroll
            for (int j = 0; j < 4; j++) {
                int n = n0 + ncol + j * 16 + lo;
                float v = acc[i][j][r] + gb[n];
                gate[(size_t)m * DM + n] = f2bf(1.0f / (1.0f + __expf(-v)));
            }
        }
}

// ---------------------------------------------------------------------------
// K3: fused windowed scan + gating + LayerNorm.
// Block = 1024 threads = all D channels for one (b, 64-step chunk);
// grid = 64 x 4 = 256 blocks = exactly 1 per CU.
// Scan in 4 groups of 16 t-rows; out_pre for a group lives in LDS (64 KB);
// then the 16 waves each LayerNorm one row and store the FINAL output.
// A = exp(A_log) <= e^-1 -> 32-step lookback truncation <= 1.3e-14.
// ---------------------------------------------------------------------------
#define CHUNK_L 64
#define LOOKBACK 32
#define GROUP 16

__global__ __launch_bounds__(1024, 4) void k_scan_ln(
    const float* __restrict__ x, const float* __restrict__ A_log,
    const float* __restrict__ Bx, const float* __restrict__ Cx,
    const float* __restrict__ Dvec, const u16* __restrict__ gate,
    const float* __restrict__ gamma, const float* __restrict__ beta,
    float* __restrict__ out)
{
    __shared__ float sBx[(CHUNK_L + LOOKBACK) * DSTATE];   // 6 KB
    __shared__ float sCx[(CHUNK_L + LOOKBACK) * DSTATE];   // 6 KB
    __shared__ float sOut[GROUP * DM];                     // 64 KB
    int d = threadIdx.x;                  // 0..1023
    int b = blockIdx.y;
    int t0 = blockIdx.x * CHUNK_L;
    int tstart = t0 - LOOKBACK; if (tstart < 0) tstart = 0;
    int lb = t0 - tstart;                 // 0 or 32
    int nv = (lb + CHUNK_L) * (DSTATE / 4);

    const f32x4* gB = (const f32x4*)(Bx + ((size_t)b * SEQ + tstart) * DSTATE);
    const f32x4* gC = (const f32x4*)(Cx + ((size_t)b * SEQ + tstart) * DSTATE);
    if (threadIdx.x < nv) {
        ((f32x4*)sBx)[threadIdx.x] = gB[threadIdx.x];
        ((f32x4*)sCx)[threadIdx.x] = gC[threadIdx.x];
    }

    float A[DSTATE], h[DSTATE];
    const f32x4* ga = (const f32x4*)(A_log + (size_t)d * DSTATE);
#pragma unroll
    for (int q = 0; q < 4; q++) {
        f32x4 av = ga[q];
#pragma unroll
        for (int c = 0; c < 4; c++) {
            A[q * 4 + c] = expf(av[c]);
            h[q * 4 + c] = 0.0f;
        }
    }
    float Dd = Dvec[d];
    __syncthreads();

    // Phase 1: lookback (no output). lb is 0 or 32; batched loads, unroll 4.
    const float* xp = x + ((size_t)b * SEQ + tstart) * DM + d;
    for (int u = 0; u < lb; u += 4) {
        float xv[4];
#pragma unroll
        for (int q = 0; q < 4; q++) xv[q] = xp[(size_t)(u + q) * DM];
#pragma unroll
        for (int q = 0; q < 4; q++) {
            int idx = u + q;
#pragma unroll
            for (int n = 0; n < DSTATE; n++)
                h[n] = h[n] * A[n] + sBx[idx * DSTATE + n] * xv[q];
        }
    }

    // Phase 2: output in groups of 16 rows, LN fused per group.
    int w    = threadIdx.x >> 6;          // wave id 0..15
    int lane = threadIdx.x & 63;
    for (int g = 0; g < CHUNK_L / GROUP; ++g) {
        int tg0 = t0 + g * GROUP;
        const float* xpg = x    + ((size_t)b * SEQ + tg0) * DM + d;
        const u16*   gpg = gate + ((size_t)b * SEQ + tg0) * DM + d;
        float xv[GROUP], gv[GROUP];
#pragma unroll
        for (int u = 0; u < GROUP; u++) xv[u] = xpg[(size_t)u * DM];
#pragma unroll
        for (int u = 0; u < GROUP; u++) gv[u] = bf2f(gpg[(size_t)u * DM]);
#pragma unroll
        for (int u = 0; u < GROUP; u++) {
            int idx = lb + g * GROUP + u;
            float y = 0.0f;
#pragma unroll
            for (int n = 0; n < DSTATE; n++) {
                h[n] = h[n] * A[n] + sBx[idx * DSTATE + n] * xv[u];
                y += h[n] * sCx[idx * DSTATE + n];
            }
            float yv = y + Dd * xv[u];
            sOut[u * DM + d] = gv[u] * yv + (1.0f - gv[u]) * xv[u];
        }
        __syncthreads();
        // LN: wave w normalizes row tg0 + w.
        {
            const float* sr = sOut + w * DM;
            f32x4 v[4];
#pragma unroll
            for (int j = 0; j < 4; j++) v[j] = ((const f32x4*)sr)[lane + 64 * j];
            float s = 0.0f, s2 = 0.0f;
#pragma unroll
            for (int j = 0; j < 4; j++)
#pragma unroll
                for (int c = 0; c < 4; c++) { float t = v[j][c]; s += t; s2 += t * t; }
#pragma unroll
            for (int off = 32; off > 0; off >>= 1) {
                s  += __shfl_down(s,  off);
                s2 += __shfl_down(s2, off);
            }
            s = __shfl(s, 0); s2 = __shfl(s2, 0);
            float mu  = s  * (1.0f / DM);
            float var = s2 * (1.0f / DM) - mu * mu;
            float rs  = rsqrtf(var + 1e-5f);
            float* op = out + ((size_t)b * SEQ + tg0 + w) * DM;
#pragma unroll
            for (int j = 0; j < 4; j++) {
                int c0 = (lane + 64 * j) * 4;
                f32x4 o;
#pragma unroll
                for (int c = 0; c < 4; c++)
                    o[c] = (v[j][c] - mu) * rs * gamma[c0 + c] + beta[c0 + c];
                *(f32x4*)(op + c0) = o;
            }
        }
        __syncthreads();
    }
}

// ---------------------------------------------------------------------------
extern "C" void kernel_launch(void* const* d_in, const int* in_sizes, int n_in,
                              void* d_out, int out_size, void* d_ws, size_t ws_size,
                              hipStream_t stream)
{
    const float* x     = (const float*)d_in[0];
    const float* A_log = (const float*)d_in[1];
    const float* Bw    = (const float*)d_in[2];
    const float* Cw    = (const float*)d_in[3];
    const float* Dv    = (const float*)d_in[4];
    const float* gw    = (const float*)d_in[5];
    const float* gb    = (const float*)d_in[6];
    const float* gam   = (const float*)d_in[7];
    const float* bet   = (const float*)d_in[8];
    float* out = (float*)d_out;

    char* ws = (char*)d_ws;
    u16*   xh   = (u16*)  ws;                             // 32 MB
    u16*   xl   = (u16*)  (ws + (32u << 20));             // 32 MB (dead after bxcx)
    u16*   gate = xl;                                     // alias: gate bf16 32 MB
    u16*   gwb  = (u16*)  (ws + (64u << 20));             // 2 MB
    u16*   bwh  = (u16*)  (ws + (66u << 20));             // 32 KB
    u16*   bwl  = (u16*)  (ws + (66u << 20) + (32u << 10));
    u16*   cwh  = (u16*)  (ws + (66u << 20) + (64u << 10));
    u16*   cwl  = (u16*)  (ws + (66u << 20) + (96u << 10));
    float* Bx   = (float*)(ws + (67u << 20));             // 1 MB
    float* Cx   = (float*)(ws + (68u << 20));             // 1 MB

    k_cvt_split<<<ROWS * DM / 4 / 256, 256, 0, stream>>>(x, xh, xl, ROWS * DM / 4);
    k_cvt_w<<<1056, 256, 0, stream>>>(gw, Bw, Cw, gwb, bwh, bwl, cwh, cwl);
    k_bxcx<<<ROWS / 16, 64, 0, stream>>>(xh, xl, bwh, bwl, cwh, cwl, Bx, Cx);
    k_gate<<<dim3(ROWS / BM, DM / BN), 256, 0, stream>>>(xh, gwb, gb, gate);
    k_scan_ln<<<dim3(SEQ / CHUNK_L, B_SZ), 1024, 0, stream>>>(
        x, A_log, Bx, Cx, Dv, gate, gam, bet, out);
}

// Round 7
// 284.016 us; speedup vs baseline: 1.0514x; 1.0514x over previous
//
#include <hip/hip_runtime.h>

#define B_SZ 4
#define SEQ  4096
#define DM   1024
#define DSTATE 16
#define ROWS (B_SZ*SEQ)   // 16384

typedef unsigned short u16;
typedef __attribute__((ext_vector_type(8))) short   s16x8;   // 8 bf16 (4 VGPRs)
typedef __attribute__((ext_vector_type(4))) float   f32x4;
typedef __attribute__((ext_vector_type(4))) u16     u16x4;

__device__ inline float bf2f(u16 u) {
    unsigned v = ((unsigned)u) << 16;
    float f; __builtin_memcpy(&f, &v, 4); return f;
}
__device__ inline u16 f2bf(float f) {
    unsigned u; __builtin_memcpy(&u, &f, 4);
    return (u16)((u + 0x7FFFu + ((u >> 16) & 1u)) >> 16);   // RNE
}
__device__ inline f32x4 mfma16(s16x8 a, s16x8 b, f32x4 c) {
    return __builtin_amdgcn_mfma_f32_16x16x32_bf16(a, b, c, 0, 0, 0);
}
// async global->LDS, 16B per lane, dest = wave-uniform base + lane*16
__device__ inline void gl_lds16(const u16* g, u16* l) {
    __builtin_amdgcn_global_load_lds(
        (const __attribute__((address_space(1))) unsigned int*)g,
        (__attribute__((address_space(3))) unsigned int*)l, 16, 0, 0);
}

// ---------------------------------------------------------------------------
// K0a: x fp32 -> xh bf16 (gate GEMM operand). xl no longer materialized —
// k_bxcx splits inline from fp32 x.
// ---------------------------------------------------------------------------
__global__ __launch_bounds__(256) void k_cvt_xh(
    const float* __restrict__ in, u16* __restrict__ oh, int n4)
{
    int i = blockIdx.x * 256 + threadIdx.x;
    if (i < n4) {
        f32x4 v = ((const f32x4*)in)[i];
        u16x4 h;
#pragma unroll
        for (int c = 0; c < 4; c++) h[c] = f2bf(v[c]);
        ((u16x4*)oh)[i] = h;
    }
}

// ---------------------------------------------------------------------------
// K0b: weight conversions in one launch.
// blocks [0,1024): gw -> gwb (bf16).  [1024,1040): Bw split. [1040,1056): Cw.
// ---------------------------------------------------------------------------
__global__ __launch_bounds__(256) void k_cvt_w(
    const float* __restrict__ gw, const float* __restrict__ Bw,
    const float* __restrict__ Cw, u16* __restrict__ gwb,
    u16* __restrict__ bwh, u16* __restrict__ bwl,
    u16* __restrict__ cwh, u16* __restrict__ cwl)
{
    int blk = blockIdx.x;
    if (blk < 1024) {
        int i = blk * 256 + threadIdx.x;
        f32x4 v = ((const f32x4*)gw)[i];
        u16x4 o;
#pragma unroll
        for (int c = 0; c < 4; c++) o[c] = f2bf(v[c]);
        ((u16x4*)gwb)[i] = o;
    } else {
        int isC = (blk >= 1040);
        const float* src = isC ? Cw : Bw;
        u16* dh = isC ? cwh : bwh;
        u16* dl = isC ? cwl : bwl;
        int i = (blk - (isC ? 1040 : 1024)) * 256 + threadIdx.x;
        f32x4 v = ((const f32x4*)src)[i];
        u16x4 h, l;
#pragma unroll
        for (int c = 0; c < 4; c++) {
            h[c] = f2bf(v[c]);
            l[c] = f2bf(v[c] - bf2f(h[c]));
        }
        ((u16x4*)dh)[i] = h;
        ((u16x4*)dl)[i] = l;
    }
}

// ---------------------------------------------------------------------------
// K1: Bx/Cx = x @ B_w^T, x @ C_w^T, 3-pass split-bf16 MFMA (fp32-grade).
// Reads x fp32 and splits hi/lo inline. One wave per 16-row M-tile.
// ---------------------------------------------------------------------------
__global__ __launch_bounds__(64) void k_bxcx(
    const float* __restrict__ x,
    const u16* __restrict__ bwh, const u16* __restrict__ bwl,
    const u16* __restrict__ cwh, const u16* __restrict__ cwl,
    float* __restrict__ Bx, float* __restrict__ Cx)
{
    int lane = threadIdx.x;
    int lo = lane & 15, hi = lane >> 4;
    int m0 = blockIdx.x * 16;
    f32x4 accB = {}, accC = {};
    for (int k0 = 0; k0 < DM; k0 += 32) {
        size_t woff = (size_t)lo * DM + k0 + hi * 8;
        s16x8 bh = *(const s16x8*)(bwh + woff);
        s16x8 bl = *(const s16x8*)(bwl + woff);
        s16x8 ch = *(const s16x8*)(cwh + woff);
        s16x8 cl = *(const s16x8*)(cwl + woff);
        size_t aoff = (size_t)(m0 + lo) * DM + k0 + hi * 8;
        f32x4 a0 = *(const f32x4*)(x + aoff);
        f32x4 a1 = *(const f32x4*)(x + aoff + 4);
        s16x8 ah, al;
#pragma unroll
        for (int c = 0; c < 4; c++) {
            u16 t;
            t = f2bf(a0[c]); ah[c] = (short)t;     al[c]     = (short)f2bf(a0[c] - bf2f(t));
            t = f2bf(a1[c]); ah[c + 4] = (short)t; al[c + 4] = (short)f2bf(a1[c] - bf2f(t));
        }
        accB = mfma16(ah, bh, accB);
        accB = mfma16(al, bh, accB);
        accB = mfma16(ah, bl, accB);
        accC = mfma16(ah, ch, accC);
        accC = mfma16(al, ch, accC);
        accC = mfma16(ah, cl, accC);
    }
#pragma unroll
    for (int r = 0; r < 4; r++) {
        int m = m0 + hi * 4 + r;
        Bx[(size_t)m * DSTATE + lo] = accB[r];
        Cx[(size_t)m * DSTATE + lo] = accC[r];
    }
}

// ---------------------------------------------------------------------------
// K2: gate = sigmoid(x @ gate_w^T + gate_b), bf16 out (ws).
// 128x128 tile, BK=64, global_load_lds w=16, XOR-swizzled 16B chunks.
// ---------------------------------------------------------------------------
#define BM 128
#define BN 128
#define BK 64

__global__ __launch_bounds__(256) void k_gate(
    const u16* __restrict__ xh, const u16* __restrict__ gwb,
    const float* __restrict__ gb, u16* __restrict__ gate)
{
    __shared__ u16 sA[BM * BK], sB[BN * BK];   // 16 KB + 16 KB
    int tid = threadIdx.x;
    int wv = tid >> 6, lane = tid & 63;
    int lo = lane & 15, hi = lane >> 4;
    int m0 = blockIdx.x * BM;
    int n0 = blockIdx.y * BN;

    int r_in = lane >> 3;          // row within 1KB staging issue (8 rows)
    int p    = lane & 7;           // physical 16B chunk slot in LDS row
    int c    = p ^ r_in;           // swizzled source chunk

    int mrow = (wv & 1) * 64;
    int ncol = (wv >> 1) * 64;

    f32x4 acc[4][4] = {};
    for (int k0 = 0; k0 < DM; k0 += BK) {
        __syncthreads();
#pragma unroll
        for (int q = 0; q < 4; q++) {
            int r = (wv * 4 + q) * 8 + r_in;            // 0..127
            size_t goff = (size_t)r * DM + k0 + c * 8;
            gl_lds16(xh  + (size_t)m0 * DM + goff, &sA[(wv * 4 + q) * 512]);
            gl_lds16(gwb + (size_t)n0 * DM + goff, &sB[(wv * 4 + q) * 512]);
        }
        __syncthreads();
#pragma unroll
        for (int kk = 0; kk < 2; kk++) {
            s16x8 bfr[4], afr[4];
#pragma unroll
            for (int j = 0; j < 4; j++) {
                int rb = ncol + j * 16 + lo;
                int pc = (kk * 4 + hi) ^ (rb & 7);
                bfr[j] = *(const s16x8*)&sB[rb * BK + pc * 8];
            }
#pragma unroll
            for (int i = 0; i < 4; i++) {
                int ra = mrow + i * 16 + lo;
                int pc = (kk * 4 + hi) ^ (ra & 7);
                afr[i] = *(const s16x8*)&sA[ra * BK + pc * 8];
            }
#pragma unroll
            for (int i = 0; i < 4; i++)
#pragma unroll
                for (int j = 0; j < 4; j++)
                    acc[i][j] = mfma16(afr[i], bfr[j], acc[i][j]);
        }
    }
#pragma unroll
    for (int i = 0; i < 4; i++)
#pragma unroll
        for (int r = 0; r < 4; r++) {
            int m = m0 + mrow + i * 16 + hi * 4 + r;
#pragma unroll
            for (int j = 0; j < 4; j++) {
                int n = n0 + ncol + j * 16 + lo;
                float v = acc[i][j][r] + gb[n];
                gate[(size_t)m * DM + n] = f2bf(1.0f / (1.0f + __expf(-v)));
            }
        }
}

// ---------------------------------------------------------------------------
// K3: windowed scan (standalone; R5 structure — independent 256t blocks for
// TLP). Reads x fp32 + gate bf16; writes out_pre fp32 into d_out.
// A = exp(A_log) <= e^-1 -> 32-step lookback truncation <= 1.3e-14.
// ---------------------------------------------------------------------------
#define CHUNK_L 64
#define LOOKBACK 32

__global__ __launch_bounds__(256) void k_scan(
    const float* __restrict__ x, const float* __restrict__ A_log,
    const float* __restrict__ Bx, const float* __restrict__ Cx,
    const float* __restrict__ Dvec, const u16* __restrict__ gate,
    float* __restrict__ out_pre)
{
    __shared__ float sBx[(CHUNK_L + LOOKBACK) * DSTATE];   // 6 KB
    __shared__ float sCx[(CHUNK_L + LOOKBACK) * DSTATE];   // 6 KB
    int d = blockIdx.x * 256 + threadIdx.x;   // 0..1023
    int b = blockIdx.z;
    int t0 = blockIdx.y * CHUNK_L;
    int tstart = t0 - LOOKBACK; if (tstart < 0) tstart = 0;
    int lb = t0 - tstart;                     // 0 or 32
    int nv = (lb + CHUNK_L) * (DSTATE / 4);

    const f32x4* gB = (const f32x4*)(Bx + ((size_t)b * SEQ + tstart) * DSTATE);
    const f32x4* gC = (const f32x4*)(Cx + ((size_t)b * SEQ + tstart) * DSTATE);
    for (int i = threadIdx.x; i < nv; i += 256) {
        ((f32x4*)sBx)[i] = gB[i];
        ((f32x4*)sCx)[i] = gC[i];
    }

    float A[DSTATE], h[DSTATE];
    const f32x4* ga = (const f32x4*)(A_log + (size_t)d * DSTATE);
#pragma unroll
    for (int q = 0; q < 4; q++) {
        f32x4 av = ga[q];
#pragma unroll
        for (int c = 0; c < 4; c++) {
            A[q * 4 + c] = expf(av[c]);
            h[q * 4 + c] = 0.0f;
        }
    }
    float Dd = Dvec[d];
    __syncthreads();

    const float* xp = x + ((size_t)b * SEQ + tstart) * DM + d;

    // Phase 1: lookback (no output). lb is 0 or 32; batched loads, unroll 4.
    for (int u = 0; u < lb; u += 4) {
        float xv[4];
#pragma unroll
        for (int q = 0; q < 4; q++) xv[q] = xp[(size_t)(u + q) * DM];
#pragma unroll
        for (int q = 0; q < 4; q++) {
            int idx = u + q;
#pragma unroll
            for (int n = 0; n < DSTATE; n++)
                h[n] = h[n] * A[n] + sBx[idx * DSTATE + n] * xv[q];
        }
    }

    // Phase 2: output steps.
    const float* xp2 = x    + ((size_t)b * SEQ + t0) * DM + d;
    const u16*   gp  = gate + ((size_t)b * SEQ + t0) * DM + d;
    float*       op  = out_pre + ((size_t)b * SEQ + t0) * DM + d;
    for (int u = 0; u < CHUNK_L; u += 4) {
        float xv[4], gv[4], ov[4];
#pragma unroll
        for (int q = 0; q < 4; q++) {
            xv[q] = xp2[(size_t)(u + q) * DM];
            gv[q] = bf2f(gp[(size_t)(u + q) * DM]);
        }
#pragma unroll
        for (int q = 0; q < 4; q++) {
            int idx = lb + u + q;
            float y = 0.0f;
#pragma unroll
            for (int n = 0; n < DSTATE; n++) {
                h[n] = h[n] * A[n] + sBx[idx * DSTATE + n] * xv[q];
                y += h[n] * sCx[idx * DSTATE + n];
            }
            float yv = y + Dd * xv[q];
            ov[q] = gv[q] * yv + (1.0f - gv[q]) * xv[q];
        }
#pragma unroll
        for (int q = 0; q < 4; q++) op[(size_t)(u + q) * DM] = ov[q];
    }
}

// ---------------------------------------------------------------------------
// K4: LayerNorm over last dim (1024), fp32, IN PLACE on d_out.
// One wave per row; each thread loads its 16 elems before any store.
// ---------------------------------------------------------------------------
__global__ __launch_bounds__(256) void k_ln(
    float* data, const float* __restrict__ gamma, const float* __restrict__ beta)
{
    int wv = threadIdx.x >> 6, lane = threadIdx.x & 63;
    int row = blockIdx.x * 4 + wv;
    f32x4* rp = (f32x4*)(data + (size_t)row * DM);
    f32x4 v[4];
#pragma unroll
    for (int j = 0; j < 4; j++) v[j] = rp[lane + 64 * j];
    float s = 0.0f, s2 = 0.0f;
#pragma unroll
    for (int j = 0; j < 4; j++)
#pragma unroll
        for (int c = 0; c < 4; c++) { float t = v[j][c]; s += t; s2 += t * t; }
#pragma unroll
    for (int off = 32; off > 0; off >>= 1) {
        s  += __shfl_down(s,  off);
        s2 += __shfl_down(s2, off);
    }
    s = __shfl(s, 0); s2 = __shfl(s2, 0);
    float mu  = s  * (1.0f / DM);
    float var = s2 * (1.0f / DM) - mu * mu;
    float rs  = rsqrtf(var + 1e-5f);
#pragma unroll
    for (int j = 0; j < 4; j++) {
        int c0 = (lane + 64 * j) * 4;
        f32x4 o;
#pragma unroll
        for (int c = 0; c < 4; c++)
            o[c] = (v[j][c] - mu) * rs * gamma[c0 + c] + beta[c0 + c];
        rp[lane + 64 * j] = o;
    }
}

// ---------------------------------------------------------------------------
extern "C" void kernel_launch(void* const* d_in, const int* in_sizes, int n_in,
                              void* d_out, int out_size, void* d_ws, size_t ws_size,
                              hipStream_t stream)
{
    const float* x     = (const float*)d_in[0];
    const float* A_log = (const float*)d_in[1];
    const float* Bw    = (const float*)d_in[2];
    const float* Cw    = (const float*)d_in[3];
    const float* Dv    = (const float*)d_in[4];
    const float* gw    = (const float*)d_in[5];
    const float* gb    = (const float*)d_in[6];
    const float* gam   = (const float*)d_in[7];
    const float* bet   = (const float*)d_in[8];
    float* out = (float*)d_out;   // out_pre fp32 -> LN in place

    char* ws = (char*)d_ws;
    u16*   xh   = (u16*)  ws;                             // 32 MB
    u16*   gate = (u16*)  (ws + (32u << 20));             // 32 MB bf16
    u16*   gwb  = (u16*)  (ws + (64u << 20));             // 2 MB
    u16*   bwh  = (u16*)  (ws + (66u << 20));             // 32 KB
    u16*   bwl  = (u16*)  (ws + (66u << 20) + (32u << 10));
    u16*   cwh  = (u16*)  (ws + (66u << 20) + (64u << 10));
    u16*   cwl  = (u16*)  (ws + (66u << 20) + (96u << 10));
    float* Bx   = (float*)(ws + (67u << 20));             // 1 MB
    float* Cx   = (float*)(ws + (68u << 20));             // 1 MB

    k_cvt_xh<<<ROWS * DM / 4 / 256, 256, 0, stream>>>(x, xh, ROWS * DM / 4);
    k_cvt_w<<<1056, 256, 0, stream>>>(gw, Bw, Cw, gwb, bwh, bwl, cwh, cwl);
    k_bxcx<<<ROWS / 16, 64, 0, stream>>>(x, bwh, bwl, cwh, cwl, Bx, Cx);
    k_gate<<<dim3(ROWS / BM, DM / BN), 256, 0, stream>>>(xh, gwb, gb, gate);
    k_scan<<<dim3(DM / 256, SEQ / CHUNK_L, B_SZ), 256, 0, stream>>>(
        x, A_log, Bx, Cx, Dv, gate, out);
    k_ln<<<ROWS / 4, 256, 0, stream>>>(out, gam, bet);
}